// Round 16
// baseline (1724.332 us; speedup 1.0000x reference)
//
#include <hip/hip_runtime.h>
#include <hip/hip_bf16.h>

#define D_DIM 512
#define S_LEN 12
#define H_NUM 8
#define WMAT 262144       // 512*512

// ---- kernel1: G_B=8, 96 rows, 12 waves, 2-head epochs, 2 col-tiles/wave ----
#define G_B1 8
#define ROWS1 96          // 6 M-tiles
#define THREADS1 768      // 12 waves
#define TBLK    6144      // 96*64 u16 elements per tensor
#define X_OFF   0         // [96][512] bf16 = 98304
#define Q_OFF   98304     // [2][96][64] u16 = 24576
#define K_OFF   122880    // [2][96][64] u16 = 24576
#define V_OFF   147456    // [96][64] u16 = 12288 (single buffer; V1 parked in regs)
#define SMEM1   159744    // <= 163840, 1 block/CU, 12 waves

// ---- kernel2 (R15-proven): G_B=8, 512 threads, Y[6][4] ----
#define G_B2 8
#define ROWS2 96
#define THREADS2 512
#define AST_OFF 0         // [96][512] bf16 = 98304
#define RED_OFF 98304     // [96][17] f32 = 6528
#define MU_OFF  104832    // [96][2] f32 = 768
#define SMEM2   105600    // 1 block/CU

// A intermediate: bf16, row r at u16-elem index r*1024 + c (low 1024 B of row r's
// 2048 B f32 slot in d_out). K2 block reads exactly the bytes it later overwrites.

typedef __attribute__((ext_vector_type(8))) short bf16x8;
typedef __attribute__((ext_vector_type(4))) float f32x4;

__device__ __forceinline__ unsigned short f2bf(float f) {
    union { float f; unsigned u; } c; c.f = f;
    unsigned r = c.u + 0x7fffu + ((c.u >> 16) & 1u);
    return (unsigned short)(r >> 16);
}
__device__ __forceinline__ float bf2f(unsigned short u) {
    union { unsigned u; float f; } c; c.u = ((unsigned)u) << 16;
    return c.f;
}
// 16B-granule XOR swizzle, 512-col tiles
__device__ __forceinline__ int xswc(int row, int col) {
    return row * 512 + (((col >> 3) ^ (row & 7)) << 3) + (col & 7);
}
// 64-col tiles, stride 64, 16B-chunk XOR
__device__ __forceinline__ int qsw(int row, int col) {
    return row * 64 + (((col >> 3) ^ (row & 7)) << 3) + (col & 7);
}

__global__ void prep_weights(const float* __restrict__ Wq, const float* __restrict__ Wk,
                             const float* __restrict__ Wv, const float* __restrict__ Wo,
                             unsigned short* __restrict__ wt) {
    int idx = blockIdx.x * 256 + threadIdx.x;   // 0 .. 4*WMAT-1
    int mat = idx >> 18;
    int rem = idx & (WMAT - 1);
    int e = rem >> 9, d = rem & 511;
    const float* W = (mat == 0) ? Wq : (mat == 1) ? Wk : (mat == 2) ? Wv : Wo;
    wt[idx] = f2bf(W[d * D_DIM + e]);           // wt[mat][e][d] = W[d][e]
}

// ---------------- kernel 1: QKV + attention -> A (bf16, packed into d_out) ----------------
__global__ __launch_bounds__(THREADS1, 3) void qkv_attn(
    const float* __restrict__ x, const unsigned short* __restrict__ wt,
    const float* __restrict__ bq, const float* __restrict__ bk, const float* __restrict__ bv,
    const float* __restrict__ adj, unsigned short* __restrict__ aout)
{
    extern __shared__ char smem[];
    unsigned short* Xh = (unsigned short*)(smem + X_OFF);
    unsigned short* Qh = (unsigned short*)(smem + Q_OFF);   // [2][96][64]
    unsigned short* Kh = (unsigned short*)(smem + K_OFF);   // [2][96][64]
    unsigned short* Vh = (unsigned short*)(smem + V_OFF);   // [96][64]

    const int tid  = threadIdx.x;
    const int lane = tid & 63;
    const int w    = tid >> 6;          // wave 0..11
    const int lr   = lane & 15;
    const int lg   = lane >> 4;
    const int lr12 = (lr < 12) ? lr : 11;       // true clamp
    const size_t row0 = (size_t)blockIdx.x * ROWS1;

    // stage X -> LDS bf16 (swizzled): 12288 float4 chunks, 16/thread
    #pragma unroll
    for (int it = 0; it < 16; ++it) {
        int idx = it * THREADS1 + tid;
        int r = idx >> 7, col = (idx & 127) << 2;
        float4 v = *(const float4*)(x + (row0 + r) * (size_t)D_DIM + col);
        ushort4 pk;
        pk.x = f2bf(v.x); pk.y = f2bf(v.y); pk.z = f2bf(v.z); pk.w = f2bf(v.w);
        *(ushort4*)(Xh + xswc(r, col)) = pk;
    }
    __syncthreads();

    // wave task: 24 tiles [mat(3)][head(2)][colt(4)]; wave w -> tiles 2w, 2w+1
    // (always same mat and same head-in-pair):
    const int mat = w >> 2;             // 0=Q,1=K,2=V
    const int hh  = (w >> 1) & 1;       // head-in-pair
    const int c0  = (w & 1) * 32;       // first col of the wave's 2 tiles
    const float* bsel = (mat == 0) ? bq : (mat == 1) ? bk : bv;
    const int rb = w * S_LEN;           // attention rows (waves 0-7)

    #pragma unroll 1
    for (int hg = 0; hg < 4; ++hg) {
        const int h = hg * 2 + hh;      // this wave's head
        // ---------------- phase A: QKV projection, 2 B-cols per A-fragment ----------------
        f32x4 acc[6][2];
        #pragma unroll
        for (int mt = 0; mt < 6; ++mt) {
            acc[mt][0] = (f32x4){0.f, 0.f, 0.f, 0.f};
            acc[mt][1] = (f32x4){0.f, 0.f, 0.f, 0.f};
        }
        const unsigned short* bp0 = wt + (size_t)mat * WMAT + (h * 64 + c0 + lr) * D_DIM + lg * 8;
        const unsigned short* bp1 = bp0 + 16 * D_DIM;
        #pragma unroll
        for (int ks = 0; ks < 16; ++ks) {
            bf16x8 b0 = *(const bf16x8*)(bp0 + ks * 32);
            bf16x8 b1 = *(const bf16x8*)(bp1 + ks * 32);
            #pragma unroll
            for (int mt = 0; mt < 6; ++mt) {
                bf16x8 af = *(const bf16x8*)(Xh + xswc(mt * 16 + lr, ks * 32 + lg * 8));
                acc[mt][0] = __builtin_amdgcn_mfma_f32_16x16x32_bf16(af, b0, acc[mt][0], 0, 0, 0);
                acc[mt][1] = __builtin_amdgcn_mfma_f32_16x16x32_bf16(af, b1, acc[mt][1], 0, 0, 0);
            }
        }
        {
            float bias0 = bsel[h * 64 + c0 + lr];
            float bias1 = bsel[h * 64 + c0 + 16 + lr];
            if (mat < 2) {
                unsigned short* T = ((mat == 0) ? Qh : Kh) + hh * TBLK;
                #pragma unroll
                for (int mt = 0; mt < 6; ++mt)
                    #pragma unroll
                    for (int j = 0; j < 4; ++j) {
                        int rowl = mt * 16 + lg * 4 + j;
                        T[qsw(rowl, c0 + lr)]      = f2bf(acc[mt][0][j] + bias0);
                        T[qsw(rowl, c0 + 16 + lr)] = f2bf(acc[mt][1][j] + bias1);
                    }
            } else if (hh == 0) {
                // V0: store now; V1 (hh==1 waves) stays parked in acc until phase C
                #pragma unroll
                for (int mt = 0; mt < 6; ++mt)
                    #pragma unroll
                    for (int j = 0; j < 4; ++j) {
                        int rowl = mt * 16 + lg * 4 + j;
                        Vh[qsw(rowl, c0 + lr)]      = f2bf(acc[mt][0][j] + bias0);
                        Vh[qsw(rowl, c0 + 16 + lr)] = f2bf(acc[mt][1][j] + bias1);
                    }
            }
        }
        __syncthreads();   // A -> B: Q0/K0/Q1/K1/V0 visible

        // ---------------- phase B: attention head hg*2 (waves 0-7, item w) ----------------
        if (w < 8) {
            const int ha = hg * 2;
            const unsigned short* Qb = Qh;          // hh=0 buffers
            const unsigned short* Kb = Kh;
            f32x4 sacc = (f32x4){0.f, 0.f, 0.f, 0.f};
            #pragma unroll
            for (int k2 = 0; k2 < 2; ++k2) {
                bf16x8 ak = *(const bf16x8*)(Kb + qsw(rb + lr12, k2 * 32 + lg * 8));
                bf16x8 aq = *(const bf16x8*)(Qb + qsw(rb + lr12, k2 * 32 + lg * 8));
                sacc = __builtin_amdgcn_mfma_f32_16x16x32_bf16(ak, aq, sacc, 0, 0, 0);
            }
            float ab4[4] = {0.f, 0.f, 0.f, 0.f};
            if (lg < 3 && lr < 12) {
                float4 t4 = *(const float4*)(adj + (ha * S_LEN + lr) * S_LEN + lg * 4);
                ab4[0] = t4.x; ab4[1] = t4.y; ab4[2] = t4.z; ab4[3] = t4.w;
            }
            float e4n[4];
            {
                float sc[4];
                float m = -1e30f;
                #pragma unroll
                for (int j = 0; j < 4; ++j) {
                    int tt = lg * 4 + j;
                    sc[j] = (tt < 12) ? (sacc[j] * 0.125f + ab4[j]) : -1e30f;
                    m = fmaxf(m, sc[j]);
                }
                m = fmaxf(m, __shfl_xor(m, 16));
                m = fmaxf(m, __shfl_xor(m, 32));
                float ssum = 0.f;
                #pragma unroll
                for (int j = 0; j < 4; ++j) { e4n[j] = __expf(sc[j] - m); ssum += e4n[j]; }
                ssum += __shfl_xor(ssum, 16);
                ssum += __shfl_xor(ssum, 32);
                float inv = 1.f / ssum;
                #pragma unroll
                for (int j = 0; j < 4; ++j) e4n[j] *= inv;
            }
            // PV via shfl broadcast: P[ss][t] lives in lane ss+16*(t>>2), reg t&3
            float vv[12];
            #pragma unroll
            for (int t = 0; t < 12; ++t) vv[t] = bf2f(Vh[qsw(rb + t, lane)]);
            #pragma unroll
            for (int ss = 0; ss < 12; ++ss) {
                float o = 0.f;
                #pragma unroll
                for (int t = 0; t < 12; ++t) {
                    float pt = __shfl(e4n[t & 3], ss + ((t >> 2) << 4));
                    o += pt * vv[t];
                }
                aout[(row0 + rb + ss) * 1024 + ha * 64 + lane] = f2bf(o);
            }
        }
        __syncthreads();   // B -> C: V0 reads done

        // ---------------- phase C: V1 waves store parked acc ----------------
        if (mat == 2 && hh == 1) {
            float bias0 = bsel[h * 64 + c0 + lr];
            float bias1 = bsel[h * 64 + c0 + 16 + lr];
            #pragma unroll
            for (int mt = 0; mt < 6; ++mt)
                #pragma unroll
                for (int j = 0; j < 4; ++j) {
                    int rowl = mt * 16 + lg * 4 + j;
                    Vh[qsw(rowl, c0 + lr)]      = f2bf(acc[mt][0][j] + bias0);
                    Vh[qsw(rowl, c0 + 16 + lr)] = f2bf(acc[mt][1][j] + bias1);
                }
        }
        __syncthreads();   // C -> D: V1 visible

        // ---------------- phase D: attention head hg*2+1 ----------------
        if (w < 8) {
            const int ha = hg * 2 + 1;
            const unsigned short* Qb = Qh + TBLK;   // hh=1 buffers
            const unsigned short* Kb = Kh + TBLK;
            f32x4 sacc = (f32x4){0.f, 0.f, 0.f, 0.f};
            #pragma unroll
            for (int k2 = 0; k2 < 2; ++k2) {
                bf16x8 ak = *(const bf16x8*)(Kb + qsw(rb + lr12, k2 * 32 + lg * 8));
                bf16x8 aq = *(const bf16x8*)(Qb + qsw(rb + lr12, k2 * 32 + lg * 8));
                sacc = __builtin_amdgcn_mfma_f32_16x16x32_bf16(ak, aq, sacc, 0, 0, 0);
            }
            float ab4[4] = {0.f, 0.f, 0.f, 0.f};
            if (lg < 3 && lr < 12) {
                float4 t4 = *(const float4*)(adj + (ha * S_LEN + lr) * S_LEN + lg * 4);
                ab4[0] = t4.x; ab4[1] = t4.y; ab4[2] = t4.z; ab4[3] = t4.w;
            }
            float e4n[4];
            {
                float sc[4];
                float m = -1e30f;
                #pragma unroll
                for (int j = 0; j < 4; ++j) {
                    int tt = lg * 4 + j;
                    sc[j] = (tt < 12) ? (sacc[j] * 0.125f + ab4[j]) : -1e30f;
                    m = fmaxf(m, sc[j]);
                }
                m = fmaxf(m, __shfl_xor(m, 16));
                m = fmaxf(m, __shfl_xor(m, 32));
                float ssum = 0.f;
                #pragma unroll
                for (int j = 0; j < 4; ++j) { e4n[j] = __expf(sc[j] - m); ssum += e4n[j]; }
                ssum += __shfl_xor(ssum, 16);
                ssum += __shfl_xor(ssum, 32);
                float inv = 1.f / ssum;
                #pragma unroll
                for (int j = 0; j < 4; ++j) e4n[j] *= inv;
            }
            float vv[12];
            #pragma unroll
            for (int t = 0; t < 12; ++t) vv[t] = bf2f(Vh[qsw(rb + t, lane)]);
            #pragma unroll
            for (int ss = 0; ss < 12; ++ss) {
                float o = 0.f;
                #pragma unroll
                for (int t = 0; t < 12; ++t) {
                    float pt = __shfl(e4n[t & 3], ss + ((t >> 2) << 4));
                    o += pt * vv[t];
                }
                aout[(row0 + rb + ss) * 1024 + ha * 64 + lane] = f2bf(o);
            }
        }
        __syncthreads();   // D -> next A: all reads done before buffers overwritten
    }
}

// ---------------- kernel 2: out-proj + bias + residual + LayerNorm (in-place) ----------------
__global__ __launch_bounds__(THREADS2, 2) void oproj_ln(
    const float* __restrict__ x, const unsigned short* __restrict__ wt,
    const float* __restrict__ bo, const float* __restrict__ gamma,
    const float* __restrict__ beta, float* __restrict__ out)
{
    extern __shared__ char smem[];
    unsigned short* Ast = (unsigned short*)(smem + AST_OFF);  // [96][512] bf16
    float* red   = (float*)(smem + RED_OFF);   // [96][17]
    float* musig = (float*)(smem + MU_OFF);    // [96][2]

    const int tid  = threadIdx.x;
    const int lane = tid & 63;
    const int w    = tid >> 6;          // wave 0..7, cols [w*64, w*64+64)
    const int lr   = lane & 15;
    const int lg   = lane >> 4;
    const size_t row0 = (size_t)blockIdx.x * ROWS2;
    const unsigned short* abase = (const unsigned short*)out;  // bf16 A region

    // stage A (bf16, low half of each row's f32 slot) -> LDS, straight 16B copy.
    #pragma unroll
    for (int it = 0; it < 12; ++it) {
        int idx = it * THREADS2 + tid;
        int r = idx >> 6, c8 = (idx & 63) << 3;
        uint4 v = *(const uint4*)(abase + (row0 + r) * 1024 + c8);
        *(uint4*)(Ast + xswc(r, c8)) = v;
    }
    __syncthreads();

    f32x4 Y[6][4];
    #pragma unroll
    for (int mt = 0; mt < 6; ++mt)
        #pragma unroll
        for (int nt = 0; nt < 4; ++nt) Y[mt][nt] = (f32x4){0.f, 0.f, 0.f, 0.f};

    const unsigned short* obase = wt + (size_t)3 * WMAT + (w * 64 + lr) * D_DIM;
    #pragma unroll 1
    for (int ks = 0; ks < 16; ++ks) {
        bf16x8 afr[6];
        #pragma unroll
        for (int mt = 0; mt < 6; ++mt)
            afr[mt] = *(const bf16x8*)(Ast + xswc(mt * 16 + lr, ks * 32 + lg * 8));
        #pragma unroll
        for (int nt = 0; nt < 4; ++nt) {
            bf16x8 bfr = *(const bf16x8*)(obase + nt * 16 * D_DIM + ks * 32 + lg * 8);
            #pragma unroll
            for (int mt = 0; mt < 6; ++mt)
                Y[mt][nt] = __builtin_amdgcn_mfma_f32_16x16x32_bf16(afr[mt], bfr, Y[mt][nt], 0, 0, 0);
        }
    }

    // epilogue: +bo, +x (fp32), LayerNorm, store
    float bo4[4], gm4[4], bt4[4];
    int cols[4];
    #pragma unroll
    for (int nt = 0; nt < 4; ++nt) {
        cols[nt] = w * 64 + nt * 16 + lr;
        bo4[nt] = bo[cols[nt]]; gm4[nt] = gamma[cols[nt]]; bt4[nt] = beta[cols[nt]];
    }
    #pragma unroll
    for (int mt = 0; mt < 6; ++mt)
        #pragma unroll
        for (int j = 0; j < 4; ++j) {
            int rowl = mt * 16 + lg * 4 + j;
            const float* xrow = x + (row0 + rowl) * (size_t)D_DIM;
            float ps = 0.f, pq = 0.f;
            #pragma unroll
            for (int nt = 0; nt < 4; ++nt) {
                float y = Y[mt][nt][j] + bo4[nt] + xrow[cols[nt]];
                Y[mt][nt][j] = y;
                ps += y; pq += y * y;
            }
            ps += __shfl_xor(ps, 1); pq += __shfl_xor(pq, 1);
            ps += __shfl_xor(ps, 2); pq += __shfl_xor(pq, 2);
            ps += __shfl_xor(ps, 4); pq += __shfl_xor(pq, 4);
            ps += __shfl_xor(ps, 8); pq += __shfl_xor(pq, 8);
            if (lr == 0) { red[rowl * 17 + w * 2] = ps; red[rowl * 17 + w * 2 + 1] = pq; }
        }
    __syncthreads();
    if (tid < ROWS2) {
        float s = 0.f, q = 0.f;
        #pragma unroll
        for (int w8 = 0; w8 < 8; ++w8) { s += red[tid * 17 + w8 * 2]; q += red[tid * 17 + w8 * 2 + 1]; }
        float mu = s * (1.f / 512.f);
        float var = q * (1.f / 512.f) - mu * mu;
        musig[tid * 2] = mu;
        musig[tid * 2 + 1] = rsqrtf(var + 1e-5f);
    }
    __syncthreads();
    #pragma unroll
    for (int mt = 0; mt < 6; ++mt)
        #pragma unroll
        for (int j = 0; j < 4; ++j) {
            int rowl = mt * 16 + lg * 4 + j;
            float mu = musig[rowl * 2], rs = musig[rowl * 2 + 1];
            float* orow = out + (row0 + rowl) * (size_t)D_DIM;
            #pragma unroll
            for (int nt = 0; nt < 4; ++nt)
                orow[cols[nt]] = (Y[mt][nt][j] - mu) * rs * gm4[nt] + bt4[nt];
        }
}

extern "C" void kernel_launch(void* const* d_in, const int* in_sizes, int n_in,
                              void* d_out, int out_size, void* d_ws, size_t ws_size,
                              hipStream_t stream) {
    (void)in_sizes; (void)n_in; (void)out_size; (void)ws_size;
    const float* x     = (const float*)d_in[0];
    const float* Wq    = (const float*)d_in[1];
    const float* bq    = (const float*)d_in[2];
    const float* Wk    = (const float*)d_in[3];
    const float* bk    = (const float*)d_in[4];
    const float* Wv    = (const float*)d_in[5];
    const float* bv    = (const float*)d_in[6];
    const float* adj   = (const float*)d_in[7];
    const float* Wo    = (const float*)d_in[8];
    const float* bo    = (const float*)d_in[9];
    const float* gamma = (const float*)d_in[10];
    const float* beta  = (const float*)d_in[11];
    unsigned short* wt = (unsigned short*)d_ws;      // 4 * 512*512 bf16 = 2 MiB

    prep_weights<<<4096, 256, 0, stream>>>(Wq, Wk, Wv, Wo, wt);
    qkv_attn<<<16384 / G_B1, THREADS1, SMEM1, stream>>>(
        x, wt, bq, bk, bv, adj, (unsigned short*)d_out);
    oproj_ln<<<16384 / G_B2, THREADS2, SMEM2, stream>>>(
        x, wt, bo, gamma, beta, (float*)d_out);
}

// Round 17
// 1274.625 us; speedup vs baseline: 1.3528x; 1.3528x over previous
//
#include <hip/hip_runtime.h>
#include <hip/hip_bf16.h>

#define D_DIM 512
#define S_LEN 12
#define H_NUM 8
#define WMAT 262144       // 512*512

// ---- kernel1: G_B=8, 96 rows, 12 waves, 1-head epochs, 32x32 MFMA QKV ----
#define G_B1 8
#define ROWS1 96          // 3 M-tiles of 32
#define THREADS1 768      // 12 waves
#define X_OFF   0         // [96][512] bf16 = 98304
#define Q_OFF   98304     // [96][64] u16 = 12288
#define K_OFF   110592
#define V_OFF   122880
#define P_OFF   135168    // 8 x [12][20] f32 = 7680
#define SMEM1   142848    // 1 block/CU

// ---- kernel2 (R15-proven): G_B=8, 512 threads, Y[6][4] ----
#define G_B2 8
#define ROWS2 96
#define THREADS2 512
#define AST_OFF 0         // [96][512] bf16 = 98304
#define RED_OFF 98304     // [96][17] f32 = 6528
#define MU_OFF  104832    // [96][2] f32 = 768
#define SMEM2   105600    // 1 block/CU

// A intermediate: bf16, row r at u16-elem index r*1024 + c (low 1024 B of row r's
// 2048 B f32 slot in d_out). K2 block reads exactly the bytes it later overwrites.

typedef __attribute__((ext_vector_type(8))) short bf16x8;
typedef __attribute__((ext_vector_type(4))) float f32x4;
typedef __attribute__((ext_vector_type(16))) float f32x16;

__device__ __forceinline__ unsigned short f2bf(float f) {
    union { float f; unsigned u; } c; c.f = f;
    unsigned r = c.u + 0x7fffu + ((c.u >> 16) & 1u);
    return (unsigned short)(r >> 16);
}
__device__ __forceinline__ float bf2f(unsigned short u) {
    union { unsigned u; float f; } c; c.u = ((unsigned)u) << 16;
    return c.f;
}
// 16B-granule XOR swizzle, 512-col tiles
__device__ __forceinline__ int xswc(int row, int col) {
    return row * 512 + (((col >> 3) ^ (row & 7)) << 3) + (col & 7);
}
// 64-col tiles, stride 64, 16B-chunk XOR
__device__ __forceinline__ int qsw(int row, int col) {
    return row * 64 + (((col >> 3) ^ (row & 7)) << 3) + (col & 7);
}

__global__ void prep_weights(const float* __restrict__ Wq, const float* __restrict__ Wk,
                             const float* __restrict__ Wv, const float* __restrict__ Wo,
                             unsigned short* __restrict__ wt) {
    int idx = blockIdx.x * 256 + threadIdx.x;   // 0 .. 4*WMAT-1
    int mat = idx >> 18;
    int rem = idx & (WMAT - 1);
    int e = rem >> 9, d = rem & 511;
    const float* W = (mat == 0) ? Wq : (mat == 1) ? Wk : (mat == 2) ? Wv : Wo;
    wt[idx] = f2bf(W[d * D_DIM + e]);           // wt[mat][e][d] = W[d][e]
}

// ---------------- kernel 1: QKV (32x32 MFMA) + attention -> A (bf16, packed) ----------------
__global__ __launch_bounds__(THREADS1, 3) void qkv_attn(
    const float* __restrict__ x, const unsigned short* __restrict__ wt,
    const float* __restrict__ bq, const float* __restrict__ bk, const float* __restrict__ bv,
    const float* __restrict__ adj, unsigned short* __restrict__ aout)
{
    extern __shared__ char smem[];
    unsigned short* Xh = (unsigned short*)(smem + X_OFF);
    unsigned short* Qh = (unsigned short*)(smem + Q_OFF);
    unsigned short* Kh = (unsigned short*)(smem + K_OFF);
    unsigned short* Vh = (unsigned short*)(smem + V_OFF);
    float* Pl = (float*)(smem + P_OFF);         // [8][12][20]

    const int tid  = threadIdx.x;
    const int lane = tid & 63;
    const int w    = tid >> 6;          // wave 0..11
    const int lr   = lane & 15;
    const int lg   = lane >> 4;
    const int lr12 = (lr < 12) ? lr : 11;       // true clamp
    const size_t row0 = (size_t)blockIdx.x * ROWS1;

    // stage X -> LDS bf16 (swizzled): 12288 float4 chunks, 16/thread
    #pragma unroll
    for (int it = 0; it < 16; ++it) {
        int idx = it * THREADS1 + tid;
        int r = idx >> 7, col = (idx & 127) << 2;
        float4 v = *(const float4*)(x + (row0 + r) * (size_t)D_DIM + col);
        ushort4 pk;
        pk.x = f2bf(v.x); pk.y = f2bf(v.y); pk.z = f2bf(v.z); pk.w = f2bf(v.w);
        *(ushort4*)(Xh + xswc(r, col)) = pk;
    }
    __syncthreads();

    // 32x32 task split: 6 tasks = mat(3) x colt(2 of 32 cols); pair (p, p+6):
    //   role 0 (waves 0-5): M-tile 0 (rows 0-31)
    //   role 1 (waves 6-11): M-tiles 1,2 (rows 32-95)
    const int p    = (w < 6) ? w : (w - 6);
    const int role = (w < 6) ? 0 : 1;
    const int mat  = p >> 1;
    const int colb = (p & 1) * 32;
    const int c32  = lane & 31;         // fragment col (B/C) and A row
    const int k8   = (lane >> 5) * 8;   // fragment k offset
    const int ro   = (lane >> 5) * 4;   // C row offset
    const float* bsel = (mat == 0) ? bq : (mat == 1) ? bk : bv;
    unsigned short* T = (mat == 0) ? Qh : (mat == 1) ? Kh : Vh;
    const int rb = w * S_LEN;           // attention rows (waves 0-7)

    #pragma unroll 1
    for (int h = 0; h < H_NUM; ++h) {
        // ---------------- QKV projection for head h (32x32x16 MFMA) ----------------
        const unsigned short* bp = wt + (size_t)mat * WMAT + (h * 64 + colb + c32) * D_DIM + k8;
        float bias = bsel[h * 64 + colb + c32];
        if (role == 0) {
            f32x16 acc;
            #pragma unroll
            for (int i = 0; i < 16; ++i) acc[i] = 0.f;
            #pragma unroll
            for (int ks = 0; ks < 32; ++ks) {
                bf16x8 b = *(const bf16x8*)(bp + ks * 16);
                bf16x8 af = *(const bf16x8*)(Xh + xswc(c32, ks * 16 + k8));
                acc = __builtin_amdgcn_mfma_f32_32x32x16_bf16(af, b, acc, 0, 0, 0);
            }
            #pragma unroll
            for (int reg = 0; reg < 16; ++reg) {
                int row = (reg & 3) + 8 * (reg >> 2) + ro;
                T[qsw(row, colb + c32)] = f2bf(acc[reg] + bias);
            }
        } else {
            f32x16 a1, a2;
            #pragma unroll
            for (int i = 0; i < 16; ++i) { a1[i] = 0.f; a2[i] = 0.f; }
            #pragma unroll
            for (int ks = 0; ks < 32; ++ks) {
                bf16x8 b = *(const bf16x8*)(bp + ks * 16);
                bf16x8 af1 = *(const bf16x8*)(Xh + xswc(32 + c32, ks * 16 + k8));
                bf16x8 af2 = *(const bf16x8*)(Xh + xswc(64 + c32, ks * 16 + k8));
                a1 = __builtin_amdgcn_mfma_f32_32x32x16_bf16(af1, b, a1, 0, 0, 0);
                a2 = __builtin_amdgcn_mfma_f32_32x32x16_bf16(af2, b, a2, 0, 0, 0);
            }
            #pragma unroll
            for (int reg = 0; reg < 16; ++reg) {
                int row = (reg & 3) + 8 * (reg >> 2) + ro;
                T[qsw(32 + row, colb + c32)] = f2bf(a1[reg] + bias);
                T[qsw(64 + row, colb + c32)] = f2bf(a2[reg] + bias);
            }
        }
        __syncthreads();   // Q/K/V complete

        // ---------------- attention (waves 0-7 <-> batch items 0-7) ----------------
        if (w < 8) {
            f32x4 sacc = (f32x4){0.f, 0.f, 0.f, 0.f};
            #pragma unroll
            for (int k2 = 0; k2 < 2; ++k2) {
                bf16x8 ak = *(const bf16x8*)(Kh + qsw(rb + lr12, k2 * 32 + lg * 8));
                bf16x8 aq = *(const bf16x8*)(Qh + qsw(rb + lr12, k2 * 32 + lg * 8));
                sacc = __builtin_amdgcn_mfma_f32_16x16x32_bf16(ak, aq, sacc, 0, 0, 0);
            }
            float ab4[4] = {0.f, 0.f, 0.f, 0.f};
            if (lg < 3 && lr < 12) {
                float4 t4 = *(const float4*)(adj + (h * S_LEN + lr) * S_LEN + lg * 4);
                ab4[0] = t4.x; ab4[1] = t4.y; ab4[2] = t4.z; ab4[3] = t4.w;
            }
            float sc[4], e4[4];
            float m = -1e30f;
            #pragma unroll
            for (int j = 0; j < 4; ++j) {
                int t = lg * 4 + j;
                sc[j] = (t < 12) ? (sacc[j] * 0.125f + ab4[j]) : -1e30f;
                m = fmaxf(m, sc[j]);
            }
            m = fmaxf(m, __shfl_xor(m, 16));
            m = fmaxf(m, __shfl_xor(m, 32));
            float ssum = 0.f;
            #pragma unroll
            for (int j = 0; j < 4; ++j) { e4[j] = __expf(sc[j] - m); ssum += e4[j]; }
            ssum += __shfl_xor(ssum, 16);
            ssum += __shfl_xor(ssum, 32);
            float inv = 1.f / ssum;
            float* Pw = Pl + w * 240;
            if (lr < 12 && lg < 3) {
                f32x4 pvec = (f32x4){e4[0] * inv, e4[1] * inv, e4[2] * inv, e4[3] * inv};
                *(f32x4*)(Pw + lr * 20 + lg * 4) = pvec;
            }
            // same-wave P write -> read: no barrier needed (validated R5-R16)
            float vv[12];
            #pragma unroll
            for (int t = 0; t < 12; ++t) vv[t] = bf2f(Vh[qsw(rb + t, lane)]);
            #pragma unroll
            for (int ss = 0; ss < 12; ++ss) {
                f32x4 pa = *(const f32x4*)(Pw + ss * 20);
                f32x4 pb = *(const f32x4*)(Pw + ss * 20 + 4);
                f32x4 pc = *(const f32x4*)(Pw + ss * 20 + 8);
                float o = 0.f;
                #pragma unroll
                for (int t = 0; t < 4; ++t) o += pa[t] * vv[t];
                #pragma unroll
                for (int t = 0; t < 4; ++t) o += pb[t] * vv[4 + t];
                #pragma unroll
                for (int t = 0; t < 4; ++t) o += pc[t] * vv[8 + t];
                // bf16 A, packed: row r's data at u16-elem r*1024 + col
                aout[(row0 + rb + ss) * 1024 + h * 64 + lane] = f2bf(o);
            }
        }
        __syncthreads();   // A consumers done; safe to overwrite Q/K/V next head
    }
}

// ---------------- kernel 2: out-proj + bias + residual + LayerNorm (in-place) ----------------
__global__ __launch_bounds__(THREADS2, 2) void oproj_ln(
    const float* __restrict__ x, const unsigned short* __restrict__ wt,
    const float* __restrict__ bo, const float* __restrict__ gamma,
    const float* __restrict__ beta, float* __restrict__ out)
{
    extern __shared__ char smem[];
    unsigned short* Ast = (unsigned short*)(smem + AST_OFF);  // [96][512] bf16
    float* red   = (float*)(smem + RED_OFF);   // [96][17]
    float* musig = (float*)(smem + MU_OFF);    // [96][2]

    const int tid  = threadIdx.x;
    const int lane = tid & 63;
    const int w    = tid >> 6;          // wave 0..7, cols [w*64, w*64+64)
    const int lr   = lane & 15;
    const int lg   = lane >> 4;
    const size_t row0 = (size_t)blockIdx.x * ROWS2;
    const unsigned short* abase = (const unsigned short*)out;  // bf16 A region

    // stage A (bf16, low half of each row's f32 slot) -> LDS, straight 16B copy.
    #pragma unroll
    for (int it = 0; it < 12; ++it) {
        int idx = it * THREADS2 + tid;
        int r = idx >> 6, c8 = (idx & 63) << 3;
        uint4 v = *(const uint4*)(abase + (row0 + r) * 1024 + c8);
        *(uint4*)(Ast + xswc(r, c8)) = v;
    }
    __syncthreads();

    f32x4 Y[6][4];
    #pragma unroll
    for (int mt = 0; mt < 6; ++mt)
        #pragma unroll
        for (int nt = 0; nt < 4; ++nt) Y[mt][nt] = (f32x4){0.f, 0.f, 0.f, 0.f};

    const unsigned short* obase = wt + (size_t)3 * WMAT + (w * 64 + lr) * D_DIM;
    #pragma unroll 1
    for (int ks = 0; ks < 16; ++ks) {
        bf16x8 afr[6];
        #pragma unroll
        for (int mt = 0; mt < 6; ++mt)
            afr[mt] = *(const bf16x8*)(Ast + xswc(mt * 16 + lr, ks * 32 + lg * 8));
        #pragma unroll
        for (int nt = 0; nt < 4; ++nt) {
            bf16x8 bfr = *(const bf16x8*)(obase + nt * 16 * D_DIM + ks * 32 + lg * 8);
            #pragma unroll
            for (int mt = 0; mt < 6; ++mt)
                Y[mt][nt] = __builtin_amdgcn_mfma_f32_16x16x32_bf16(afr[mt], bfr, Y[mt][nt], 0, 0, 0);
        }
    }

    // epilogue: +bo, +x (fp32), LayerNorm, store
    float bo4[4], gm4[4], bt4[4];
    int cols[4];
    #pragma unroll
    for (int nt = 0; nt < 4; ++nt) {
        cols[nt] = w * 64 + nt * 16 + lr;
        bo4[nt] = bo[cols[nt]]; gm4[nt] = gamma[cols[nt]]; bt4[nt] = beta[cols[nt]];
    }
    #pragma unroll
    for (int mt = 0; mt < 6; ++mt)
        #pragma unroll
        for (int j = 0; j < 4; ++j) {
            int rowl = mt * 16 + lg * 4 + j;
            const float* xrow = x + (row0 + rowl) * (size_t)D_DIM;
            float ps = 0.f, pq = 0.f;
            #pragma unroll
            for (int nt = 0; nt < 4; ++nt) {
                float y = Y[mt][nt][j] + bo4[nt] + xrow[cols[nt]];
                Y[mt][nt][j] = y;
                ps += y; pq += y * y;
            }
            ps += __shfl_xor(ps, 1); pq += __shfl_xor(pq, 1);
            ps += __shfl_xor(ps, 2); pq += __shfl_xor(pq, 2);
            ps += __shfl_xor(ps, 4); pq += __shfl_xor(pq, 4);
            ps += __shfl_xor(ps, 8); pq += __shfl_xor(pq, 8);
            if (lr == 0) { red[rowl * 17 + w * 2] = ps; red[rowl * 17 + w * 2 + 1] = pq; }
        }
    __syncthreads();
    if (tid < ROWS2) {
        float s = 0.f, q = 0.f;
        #pragma unroll
        for (int w8 = 0; w8 < 8; ++w8) { s += red[tid * 17 + w8 * 2]; q += red[tid * 17 + w8 * 2 + 1]; }
        float mu = s * (1.f / 512.f);
        float var = q * (1.f / 512.f) - mu * mu;
        musig[tid * 2] = mu;
        musig[tid * 2 + 1] = rsqrtf(var + 1e-5f);
    }
    __syncthreads();
    #pragma unroll
    for (int mt = 0; mt < 6; ++mt)
        #pragma unroll
        for (int j = 0; j < 4; ++j) {
            int rowl = mt * 16 + lg * 4 + j;
            float mu = musig[rowl * 2], rs = musig[rowl * 2 + 1];
            float* orow = out + (row0 + rowl) * (size_t)D_DIM;
            #pragma unroll
            for (int nt = 0; nt < 4; ++nt)
                orow[cols[nt]] = (Y[mt][nt][j] - mu) * rs * gm4[nt] + bt4[nt];
        }
}

extern "C" void kernel_launch(void* const* d_in, const int* in_sizes, int n_in,
                              void* d_out, int out_size, void* d_ws, size_t ws_size,
                              hipStream_t stream) {
    (void)in_sizes; (void)n_in; (void)out_size; (void)ws_size;
    const float* x     = (const float*)d_in[0];
    const float* Wq    = (const float*)d_in[1];
    const float* bq    = (const float*)d_in[2];
    const float* Wk    = (const float*)d_in[3];
    const float* bk    = (const float*)d_in[4];
    const float* Wv    = (const float*)d_in[5];
    const float* bv    = (const float*)d_in[6];
    const float* adj   = (const float*)d_in[7];
    const float* Wo    = (const float*)d_in[8];
    const float* bo    = (const float*)d_in[9];
    const float* gamma = (const float*)d_in[10];
    const float* beta  = (const float*)d_in[11];
    unsigned short* wt = (unsigned short*)d_ws;      // 4 * 512*512 bf16 = 2 MiB

    prep_weights<<<4096, 256, 0, stream>>>(Wq, Wk, Wv, Wo, wt);
    qkv_attn<<<16384 / G_B1, THREADS1, SMEM1, stream>>>(
        x, wt, bq, bk, bv, adj, (unsigned short*)d_out);
    oproj_ln<<<16384 / G_B2, THREADS2, SMEM2, stream>>>(
        x, wt, bo, gamma, beta, (float*)d_out);
}

// Round 18
// 1051.145 us; speedup vs baseline: 1.6404x; 1.2126x over previous
//
#include <hip/hip_runtime.h>
#include <hip/hip_bf16.h>

#define D_DIM 512
#define S_LEN 12
#define H_NUM 8
#define WMAT 262144       // 512*512

// ---- fused kernel: G_B=8, 96 rows, 12 waves ----
#define G_B 8
#define ROWS 96           // 6 M-tiles
#define THREADS 768       // 12 waves
#define X_OFF   0         // [96][512] bf16 = 98304 (reused as A-tile in phase 2+)
#define Q_OFF   98304     // [96][64] bf16 = 12288
#define K_OFF   110592
#define V_OFF   122880
#define P_OFF   135168    // phase 1: 8 x [12][20] f32 ; phase 4: red[96][9]+musig[96][2]
#define SMEM    142848    // 1 block/CU

// A intermediate: bf16, row r at u16-elem index r*1024 + c (low 1024 B of row r's
// 2048 B f32 slot in d_out). Same block writes then reads then overwrites -> safe.

typedef __attribute__((ext_vector_type(8))) short bf16x8;
typedef __attribute__((ext_vector_type(4))) float f32x4;

__device__ __forceinline__ unsigned short f2bf(float f) {
    union { float f; unsigned u; } c; c.f = f;
    unsigned r = c.u + 0x7fffu + ((c.u >> 16) & 1u);
    return (unsigned short)(r >> 16);
}
__device__ __forceinline__ float bf2f(unsigned short u) {
    union { unsigned u; float f; } c; c.u = ((unsigned)u) << 16;
    return c.f;
}
// 16B-granule XOR swizzle, 512-col tiles
__device__ __forceinline__ int xswc(int row, int col) {
    return row * 512 + (((col >> 3) ^ (row & 7)) << 3) + (col & 7);
}
// 64-col tiles, stride 64, 16B-chunk XOR
__device__ __forceinline__ int qsw(int row, int col) {
    return row * 64 + (((col >> 3) ^ (row & 7)) << 3) + (col & 7);
}

__global__ void prep_weights(const float* __restrict__ Wq, const float* __restrict__ Wk,
                             const float* __restrict__ Wv, const float* __restrict__ Wo,
                             unsigned short* __restrict__ wt) {
    int idx = blockIdx.x * 256 + threadIdx.x;   // 0 .. 4*WMAT-1
    int mat = idx >> 18;
    int rem = idx & (WMAT - 1);
    int e = rem >> 9, d = rem & 511;
    const float* W = (mat == 0) ? Wq : (mat == 1) ? Wk : (mat == 2) ? Wv : Wo;
    wt[idx] = f2bf(W[d * D_DIM + e]);           // wt[mat][e][d] = W[d][e]
}

// ---------------- fused: QKV + attention + out-proj + residual + LayerNorm ----------------
__global__ __launch_bounds__(THREADS, 3) void fused_all(
    const float* __restrict__ x, const unsigned short* __restrict__ wt,
    const float* __restrict__ bq, const float* __restrict__ bk, const float* __restrict__ bv,
    const float* __restrict__ adj, const float* __restrict__ bo,
    const float* __restrict__ gamma, const float* __restrict__ beta,
    float* __restrict__ out)
{
    extern __shared__ char smem[];
    unsigned short* Xh = (unsigned short*)(smem + X_OFF);   // X, later A
    unsigned short* Qh = (unsigned short*)(smem + Q_OFF);
    unsigned short* Kh = (unsigned short*)(smem + K_OFF);
    unsigned short* Vh = (unsigned short*)(smem + V_OFF);
    float* Pl    = (float*)(smem + P_OFF);                  // [8][12][20]
    float* red   = (float*)(smem + P_OFF);                  // [96][9] (phase 4)
    float* musig = (float*)(smem + P_OFF + 3456);           // [96][2]

    unsigned short* aout = (unsigned short*)out;            // bf16 A region

    const int tid  = threadIdx.x;
    const int lane = tid & 63;
    const int w    = tid >> 6;          // wave 0..11
    const int lr   = lane & 15;
    const int lg   = lane >> 4;
    const int lr12 = (lr < 12) ? lr : 11;       // true clamp
    const size_t row0 = (size_t)blockIdx.x * ROWS;

    // ---------------- phase 0: stage X -> LDS bf16 (swizzled) ----------------
    #pragma unroll
    for (int it = 0; it < 16; ++it) {
        int idx = it * THREADS + tid;
        int r = idx >> 7, col = (idx & 127) << 2;
        float4 v = *(const float4*)(x + (row0 + r) * (size_t)D_DIM + col);
        ushort4 pk;
        pk.x = f2bf(v.x); pk.y = f2bf(v.y); pk.z = f2bf(v.z); pk.w = f2bf(v.w);
        *(ushort4*)(Xh + xswc(r, col)) = pk;
    }
    __syncthreads();

    // ---------------- phase 1: head loop (R15-proven, verbatim) ----------------
    const int mat  = w >> 2;
    const int colt = w & 3;
    const int colh = colt * 16 + lr;
    const float* bsel = (mat == 0) ? bq : (mat == 1) ? bk : bv;
    unsigned short* T = (mat == 0) ? Qh : (mat == 1) ? Kh : Vh;
    const int rb = w * S_LEN;

    #pragma unroll 1
    for (int h = 0; h < H_NUM; ++h) {
        f32x4 acc[6];
        #pragma unroll
        for (int mt = 0; mt < 6; ++mt) acc[mt] = (f32x4){0.f, 0.f, 0.f, 0.f};

        const unsigned short* bAp = wt + (size_t)mat * WMAT + (h * 64 + colh) * D_DIM + lg * 8;
        bf16x8 bc = *(const bf16x8*)(bAp);
        #pragma unroll
        for (int ks = 0; ks < 16; ++ks) {
            bf16x8 bn;
            if (ks < 15) bn = *(const bf16x8*)(bAp + (ks + 1) * 32);
            #pragma unroll
            for (int mt = 0; mt < 6; ++mt) {
                bf16x8 af = *(const bf16x8*)(Xh + xswc(mt * 16 + lr, ks * 32 + lg * 8));
                acc[mt] = __builtin_amdgcn_mfma_f32_16x16x32_bf16(af, bc, acc[mt], 0, 0, 0);
            }
            if (ks < 15) bc = bn;
        }
        {
            float bias = bsel[h * 64 + colh];
            #pragma unroll
            for (int mt = 0; mt < 6; ++mt)
                #pragma unroll
                for (int j = 0; j < 4; ++j)
                    T[qsw(mt * 16 + lg * 4 + j, colh)] = f2bf(acc[mt][j] + bias);
        }
        __syncthreads();   // Q/K/V complete

        if (w < 8) {
            f32x4 sacc = (f32x4){0.f, 0.f, 0.f, 0.f};
            #pragma unroll
            for (int k2 = 0; k2 < 2; ++k2) {
                bf16x8 ak = *(const bf16x8*)(Kh + qsw(rb + lr12, k2 * 32 + lg * 8));
                bf16x8 aq = *(const bf16x8*)(Qh + qsw(rb + lr12, k2 * 32 + lg * 8));
                sacc = __builtin_amdgcn_mfma_f32_16x16x32_bf16(ak, aq, sacc, 0, 0, 0);
            }
            float ab4[4] = {0.f, 0.f, 0.f, 0.f};
            if (lg < 3 && lr < 12) {
                float4 t4 = *(const float4*)(adj + (h * S_LEN + lr) * S_LEN + lg * 4);
                ab4[0] = t4.x; ab4[1] = t4.y; ab4[2] = t4.z; ab4[3] = t4.w;
            }
            float sc[4], e4[4];
            float m = -1e30f;
            #pragma unroll
            for (int j = 0; j < 4; ++j) {
                int t = lg * 4 + j;
                sc[j] = (t < 12) ? (sacc[j] * 0.125f + ab4[j]) : -1e30f;
                m = fmaxf(m, sc[j]);
            }
            m = fmaxf(m, __shfl_xor(m, 16));
            m = fmaxf(m, __shfl_xor(m, 32));
            float ssum = 0.f;
            #pragma unroll
            for (int j = 0; j < 4; ++j) { e4[j] = __expf(sc[j] - m); ssum += e4[j]; }
            ssum += __shfl_xor(ssum, 16);
            ssum += __shfl_xor(ssum, 32);
            float inv = 1.f / ssum;
            float* Pw = Pl + w * 240;
            if (lr < 12 && lg < 3) {
                f32x4 pvec = (f32x4){e4[0] * inv, e4[1] * inv, e4[2] * inv, e4[3] * inv};
                *(f32x4*)(Pw + lr * 20 + lg * 4) = pvec;
            }
            float vv[12];
            #pragma unroll
            for (int t = 0; t < 12; ++t) vv[t] = bf2f(Vh[qsw(rb + t, lane)]);
            #pragma unroll
            for (int ss = 0; ss < 12; ++ss) {
                f32x4 pa = *(const f32x4*)(Pw + ss * 20);
                f32x4 pb = *(const f32x4*)(Pw + ss * 20 + 4);
                f32x4 pc = *(const f32x4*)(Pw + ss * 20 + 8);
                float o = 0.f;
                #pragma unroll
                for (int t = 0; t < 4; ++t) o += pa[t] * vv[t];
                #pragma unroll
                for (int t = 0; t < 4; ++t) o += pb[t] * vv[4 + t];
                #pragma unroll
                for (int t = 0; t < 4; ++t) o += pc[t] * vv[8 + t];
                aout[(row0 + rb + ss) * 1024 + h * 64 + lane] = f2bf(o);
            }
        }
        __syncthreads();   // A consumers done; safe to overwrite Q/K/V next head
    }

    // ---------------- phase 2: stage A (global bf16, same block's rows) -> X region ----------------
    // barrier above + vmcnt drain makes this block's A-writes visible to itself.
    #pragma unroll
    for (int it = 0; it < 8; ++it) {
        int idx = it * THREADS + tid;
        int r = idx >> 6, c8 = (idx & 63) << 3;
        uint4 v = *(const uint4*)(aout + (row0 + r) * 1024 + c8);
        *(uint4*)(Xh + xswc(r, c8)) = v;
    }
    __syncthreads();

    // ---------------- phase 3: out-projection, wave = (rg, cg) ----------------
    // rg = w>>2 (rows rg*32..+31, 2 M-tiles), cg = w&3 (cols cg*128..+127, 8 N-tiles)
    const int rg = w >> 2;
    const int cg = w & 3;
    f32x4 Y[2][8];
    #pragma unroll
    for (int mt = 0; mt < 2; ++mt)
        #pragma unroll
        for (int nt = 0; nt < 8; ++nt) Y[mt][nt] = (f32x4){0.f, 0.f, 0.f, 0.f};

    const unsigned short* obase = wt + (size_t)3 * WMAT + (cg * 128 + lr) * D_DIM;
    #pragma unroll 1
    for (int ks = 0; ks < 16; ++ks) {
        bf16x8 af0 = *(const bf16x8*)(Xh + xswc(rg * 32 + lr,      ks * 32 + lg * 8));
        bf16x8 af1 = *(const bf16x8*)(Xh + xswc(rg * 32 + 16 + lr, ks * 32 + lg * 8));
        #pragma unroll
        for (int nt = 0; nt < 8; ++nt) {
            bf16x8 bfr = *(const bf16x8*)(obase + nt * 16 * D_DIM + ks * 32 + lg * 8);
            Y[0][nt] = __builtin_amdgcn_mfma_f32_16x16x32_bf16(af0, bfr, Y[0][nt], 0, 0, 0);
            Y[1][nt] = __builtin_amdgcn_mfma_f32_16x16x32_bf16(af1, bfr, Y[1][nt], 0, 0, 0);
        }
    }

    // ---------------- phase 4: +bo, +x, LayerNorm reduce ----------------
    #pragma unroll
    for (int mt = 0; mt < 2; ++mt)
        #pragma unroll
        for (int j = 0; j < 4; ++j) {
            int rowl = rg * 32 + mt * 16 + lg * 4 + j;
            const float* xrow = x + (row0 + rowl) * (size_t)D_DIM;
            float ps = 0.f, pq = 0.f;
            #pragma unroll
            for (int nt = 0; nt < 8; ++nt) {
                int c = cg * 128 + nt * 16 + lr;
                float y = Y[mt][nt][j] + bo[c] + xrow[c];
                Y[mt][nt][j] = y;
                ps += y; pq += y * y;
            }
            ps += __shfl_xor(ps, 1); pq += __shfl_xor(pq, 1);
            ps += __shfl_xor(ps, 2); pq += __shfl_xor(pq, 2);
            ps += __shfl_xor(ps, 4); pq += __shfl_xor(pq, 4);
            ps += __shfl_xor(ps, 8); pq += __shfl_xor(pq, 8);
            if (lr == 0) { red[rowl * 9 + cg * 2] = ps; red[rowl * 9 + cg * 2 + 1] = pq; }
        }
    __syncthreads();
    if (tid < ROWS) {
        float s = 0.f, q = 0.f;
        #pragma unroll
        for (int c4 = 0; c4 < 4; ++c4) { s += red[tid * 9 + c4 * 2]; q += red[tid * 9 + c4 * 2 + 1]; }
        float mu = s * (1.f / 512.f);
        float var = q * (1.f / 512.f) - mu * mu;
        musig[tid * 2] = mu;
        musig[tid * 2 + 1] = rsqrtf(var + 1e-5f);
    }
    __syncthreads();

    // ---------------- phase 5: normalize + store f32 ----------------
    #pragma unroll
    for (int mt = 0; mt < 2; ++mt)
        #pragma unroll
        for (int j = 0; j < 4; ++j) {
            int rowl = rg * 32 + mt * 16 + lg * 4 + j;
            float mu = musig[rowl * 2], rs = musig[rowl * 2 + 1];
            float* orow = out + (row0 + rowl) * (size_t)D_DIM;
            #pragma unroll
            for (int nt = 0; nt < 8; ++nt) {
                int c = cg * 128 + nt * 16 + lr;
                orow[c] = (Y[mt][nt][j] - mu) * rs * gamma[c] + beta[c];
            }
        }
}

extern "C" void kernel_launch(void* const* d_in, const int* in_sizes, int n_in,
                              void* d_out, int out_size, void* d_ws, size_t ws_size,
                              hipStream_t stream) {
    (void)in_sizes; (void)n_in; (void)out_size; (void)ws_size;
    const float* x     = (const float*)d_in[0];
    const float* Wq    = (const float*)d_in[1];
    const float* bq    = (const float*)d_in[2];
    const float* Wk    = (const float*)d_in[3];
    const float* bk    = (const float*)d_in[4];
    const float* Wv    = (const float*)d_in[5];
    const float* bv    = (const float*)d_in[6];
    const float* adj   = (const float*)d_in[7];
    const float* Wo    = (const float*)d_in[8];
    const float* bo    = (const float*)d_in[9];
    const float* gamma = (const float*)d_in[10];
    const float* beta  = (const float*)d_in[11];
    unsigned short* wt = (unsigned short*)d_ws;      // 4 * 512*512 bf16 = 2 MiB

    prep_weights<<<4096, 256, 0, stream>>>(Wq, Wk, Wv, Wo, wt);
    fused_all<<<16384 / G_B, THREADS, SMEM, stream>>>(
        x, wt, bq, bk, bv, adj, bo, gamma, beta, (float*)d_out);
}

// Round 19
// 1012.879 us; speedup vs baseline: 1.7024x; 1.0378x over previous
//
#include <hip/hip_runtime.h>
#include <hip/hip_bf16.h>

#define D_DIM 512
#define S_LEN 12
#define H_NUM 8
#define WMAT 262144       // 512*512

// ---- kernel1: G_B=8, 96 rows, 12 waves, 2-head epochs, K-chunked X staging ----
#define G_B1 8
#define ROWS1 96          // 6 M-tiles
#define THREADS1 768      // 12 waves
#define TBLK    6144      // 96*64 u16 per tensor
#define XC_OFF  0         // 2 x [96][128] bf16 chunk double-buffer = 49152
#define XCB     24576     // bytes per chunk buffer
#define Q_OFF   49152     // [2][96][64] u16 = 24576
#define K_OFF   73728
#define V_OFF   98304
#define P_OFF   122880    // 16 x [12][20] f32 = 15360
#define SMEM1   138240    // <= 163840, 1 block/CU, 12 waves

// ---- kernel2 (R15-proven): G_B=8, 512 threads, Y[6][4] ----
#define G_B2 8
#define ROWS2 96
#define THREADS2 512
#define AST_OFF 0         // [96][512] bf16 = 98304
#define RED_OFF 98304     // [96][17] f32 = 6528
#define MU_OFF  104832    // [96][2] f32 = 768
#define SMEM2   105600    // 1 block/CU

// A intermediate: bf16, row r at u16-elem index r*1024 + c (low 1024 B of row r's
// 2048 B f32 slot in d_out). K2 block reads exactly the bytes it later overwrites.

typedef __attribute__((ext_vector_type(8))) short bf16x8;
typedef __attribute__((ext_vector_type(4))) float f32x4;

__device__ __forceinline__ unsigned short f2bf(float f) {
    union { float f; unsigned u; } c; c.f = f;
    unsigned r = c.u + 0x7fffu + ((c.u >> 16) & 1u);
    return (unsigned short)(r >> 16);
}
__device__ __forceinline__ float bf2f(unsigned short u) {
    union { unsigned u; float f; } c; c.u = ((unsigned)u) << 16;
    return c.f;
}
// 16B-granule XOR swizzle, 512-col tiles (K2 A-tile)
__device__ __forceinline__ int xswc(int row, int col) {
    return row * 512 + (((col >> 3) ^ (row & 7)) << 3) + (col & 7);
}
// 128-col chunk tiles (K1 X chunks)
__device__ __forceinline__ int xcs(int row, int col) {
    return row * 128 + (((col >> 3) ^ (row & 7)) << 3) + (col & 7);
}
// 64-col tiles, stride 64, 16B-chunk XOR
__device__ __forceinline__ int qsw(int row, int col) {
    return row * 64 + (((col >> 3) ^ (row & 7)) << 3) + (col & 7);
}

__global__ void prep_weights(const float* __restrict__ Wq, const float* __restrict__ Wk,
                             const float* __restrict__ Wv, const float* __restrict__ Wo,
                             unsigned short* __restrict__ wt) {
    int idx = blockIdx.x * 256 + threadIdx.x;   // 0 .. 4*WMAT-1
    int mat = idx >> 18;
    int rem = idx & (WMAT - 1);
    int e = rem >> 9, d = rem & 511;
    const float* W = (mat == 0) ? Wq : (mat == 1) ? Wk : (mat == 2) ? Wv : Wo;
    wt[idx] = f2bf(W[d * D_DIM + e]);           // wt[mat][e][d] = W[d][e]
}

// ---------------- kernel 1: QKV (2-head epochs) + attention -> A (bf16, packed) ----------------
__global__ __launch_bounds__(THREADS1, 3) void qkv_attn(
    const float* __restrict__ x, const unsigned short* __restrict__ wt,
    const float* __restrict__ bq, const float* __restrict__ bk, const float* __restrict__ bv,
    const float* __restrict__ adj, unsigned short* __restrict__ aout)
{
    extern __shared__ char smem[];
    unsigned short* Xc = (unsigned short*)(smem + XC_OFF);  // 2 chunk buffers
    unsigned short* Qh = (unsigned short*)(smem + Q_OFF);   // [2][96][64]
    unsigned short* Kh = (unsigned short*)(smem + K_OFF);
    unsigned short* Vh = (unsigned short*)(smem + V_OFF);
    float* Pl = (float*)(smem + P_OFF);         // [16][12][20]

    const int tid  = threadIdx.x;
    const int lane = tid & 63;
    const int w    = tid >> 6;          // wave 0..11
    const int lr   = lane & 15;
    const int lg   = lane >> 4;
    const int lr12 = (lr < 12) ? lr : 11;       // true clamp
    const size_t row0 = (size_t)blockIdx.x * ROWS1;

    // wave task: mat = w>>2 (0=Q,1=K,2=V), colt = w&3; 2 cols = same colt of both heads
    const int mat  = w >> 2;
    const int colt = w & 3;
    const int colh = colt * 16 + lr;
    const float* bsel = (mat == 0) ? bq : (mat == 1) ? bk : bv;
    unsigned short* Tbase = (mat == 0) ? Qh : (mat == 1) ? Kh : Vh;

    // staging lambda-equivalent: chunk c -> buffer (c&1)
    // idx over 96x32 float4-chunks = 3072, 4 per thread
#define STAGE_CHUNK(c)                                                          \
    {                                                                           \
        unsigned short* dst = Xc + ((c) & 1) * (XCB / 2);                       \
        _Pragma("unroll")                                                       \
        for (int it = 0; it < 4; ++it) {                                        \
            int idx = it * THREADS1 + tid;                                      \
            int r = idx >> 5, col = (idx & 31) << 2;                            \
            float4 v = *(const float4*)(x + (row0 + r) * (size_t)D_DIM + (c) * 128 + col); \
            ushort4 pk;                                                         \
            pk.x = f2bf(v.x); pk.y = f2bf(v.y); pk.z = f2bf(v.z); pk.w = f2bf(v.w); \
            *(ushort4*)(dst + xcs(r, col)) = pk;                                \
        }                                                                       \
    }

    #pragma unroll 1
    for (int ep = 0; ep < 4; ++ep) {
        const int h0 = ep * 2, h1 = ep * 2 + 1;
        // ---------------- QKV projection: 2 heads, K-chunked ----------------
        f32x4 accA[6], accB[6];
        #pragma unroll
        for (int mt = 0; mt < 6; ++mt) {
            accA[mt] = (f32x4){0.f, 0.f, 0.f, 0.f};
            accB[mt] = (f32x4){0.f, 0.f, 0.f, 0.f};
        }
        const unsigned short* b0base = wt + (size_t)mat * WMAT + (h0 * 64 + colh) * D_DIM + lg * 8;
        const unsigned short* b1base = wt + (size_t)mat * WMAT + (h1 * 64 + colh) * D_DIM + lg * 8;

        STAGE_CHUNK(0)
        __syncthreads();
        #pragma unroll
        for (int c = 0; c < 4; ++c) {
            if (c < 3) STAGE_CHUNK(c + 1)       // overlaps with compute below
            const unsigned short* Xb = Xc + (c & 1) * (XCB / 2);
            #pragma unroll
            for (int kk = 0; kk < 4; ++kk) {
                bf16x8 b0 = *(const bf16x8*)(b0base + c * 128 + kk * 32);
                bf16x8 b1 = *(const bf16x8*)(b1base + c * 128 + kk * 32);
                #pragma unroll
                for (int mt = 0; mt < 6; ++mt) {
                    bf16x8 af = *(const bf16x8*)(Xb + xcs(mt * 16 + lr, kk * 32 + lg * 8));
                    accA[mt] = __builtin_amdgcn_mfma_f32_16x16x32_bf16(af, b0, accA[mt], 0, 0, 0);
                    accB[mt] = __builtin_amdgcn_mfma_f32_16x16x32_bf16(af, b1, accB[mt], 0, 0, 0);
                }
            }
            __syncthreads();                    // staged chunk visible; buffer reusable
        }
        // store both heads' tiles (+bias) — unconditional, immediate
        {
            float bias0 = bsel[h0 * 64 + colh];
            float bias1 = bsel[h1 * 64 + colh];
            #pragma unroll
            for (int mt = 0; mt < 6; ++mt)
                #pragma unroll
                for (int j = 0; j < 4; ++j) {
                    int rowl = mt * 16 + lg * 4 + j;
                    Tbase[qsw(rowl, colh)]        = f2bf(accA[mt][j] + bias0);
                    Tbase[TBLK + qsw(rowl, colh)] = f2bf(accB[mt][j] + bias1);
                }
        }
        __syncthreads();   // Q/K/V of both heads visible

        // ---------------- attention: 16 tasks (item, head) over 12 waves ----------------
        for (int t = w; t < 16; t += 12) {
            const int item = t & 7;
            const int hh2  = t >> 3;
            const int h    = ep * 2 + hh2;
            const int rbA  = item * S_LEN;
            const unsigned short* Qb = Qh + hh2 * TBLK;
            const unsigned short* Kb = Kh + hh2 * TBLK;
            const unsigned short* Vb = Vh + hh2 * TBLK;

            f32x4 sacc = (f32x4){0.f, 0.f, 0.f, 0.f};
            #pragma unroll
            for (int k2 = 0; k2 < 2; ++k2) {
                bf16x8 ak = *(const bf16x8*)(Kb + qsw(rbA + lr12, k2 * 32 + lg * 8));
                bf16x8 aq = *(const bf16x8*)(Qb + qsw(rbA + lr12, k2 * 32 + lg * 8));
                sacc = __builtin_amdgcn_mfma_f32_16x16x32_bf16(ak, aq, sacc, 0, 0, 0);
            }
            float ab4[4] = {0.f, 0.f, 0.f, 0.f};
            if (lg < 3 && lr < 12) {
                float4 t4 = *(const float4*)(adj + (h * S_LEN + lr) * S_LEN + lg * 4);
                ab4[0] = t4.x; ab4[1] = t4.y; ab4[2] = t4.z; ab4[3] = t4.w;
            }
            float sc[4], e4[4];
            float m = -1e30f;
            #pragma unroll
            for (int j = 0; j < 4; ++j) {
                int tt = lg * 4 + j;
                sc[j] = (tt < 12) ? (sacc[j] * 0.125f + ab4[j]) : -1e30f;
                m = fmaxf(m, sc[j]);
            }
            m = fmaxf(m, __shfl_xor(m, 16));
            m = fmaxf(m, __shfl_xor(m, 32));
            float ssum = 0.f;
            #pragma unroll
            for (int j = 0; j < 4; ++j) { e4[j] = __expf(sc[j] - m); ssum += e4[j]; }
            ssum += __shfl_xor(ssum, 16);
            ssum += __shfl_xor(ssum, 32);
            float inv = 1.f / ssum;
            float* Pw = Pl + t * 240;
            if (lr < 12 && lg < 3) {
                f32x4 pvec = (f32x4){e4[0] * inv, e4[1] * inv, e4[2] * inv, e4[3] * inv};
                *(f32x4*)(Pw + lr * 20 + lg * 4) = pvec;
            }
            // same-wave P write -> read: no barrier needed (validated R5-R18)
            float vv[12];
            #pragma unroll
            for (int t2 = 0; t2 < 12; ++t2) vv[t2] = bf2f(Vb[qsw(rbA + t2, lane)]);
            #pragma unroll
            for (int ss = 0; ss < 12; ++ss) {
                f32x4 pa = *(const f32x4*)(Pw + ss * 20);
                f32x4 pb = *(const f32x4*)(Pw + ss * 20 + 4);
                f32x4 pc = *(const f32x4*)(Pw + ss * 20 + 8);
                float o = 0.f;
                #pragma unroll
                for (int t2 = 0; t2 < 4; ++t2) o += pa[t2] * vv[t2];
                #pragma unroll
                for (int t2 = 0; t2 < 4; ++t2) o += pb[t2] * vv[4 + t2];
                #pragma unroll
                for (int t2 = 0; t2 < 4; ++t2) o += pc[t2] * vv[8 + t2];
                // bf16 A, packed: row r's data at u16-elem r*1024 + col
                aout[(row0 + rbA + ss) * 1024 + h * 64 + lane] = f2bf(o);
            }
        }
        __syncthreads();   // attn reads done before next epoch overwrites Xc/QKV
    }
#undef STAGE_CHUNK
}

// ---------------- kernel 2: out-proj + bias + residual + LayerNorm (in-place) ----------------
__global__ __launch_bounds__(THREADS2, 2) void oproj_ln(
    const float* __restrict__ x, const unsigned short* __restrict__ wt,
    const float* __restrict__ bo, const float* __restrict__ gamma,
    const float* __restrict__ beta, float* __restrict__ out)
{
    extern __shared__ char smem[];
    unsigned short* Ast = (unsigned short*)(smem + AST_OFF);  // [96][512] bf16
    float* red   = (float*)(smem + RED_OFF);   // [96][17]
    float* musig = (float*)(smem + MU_OFF);    // [96][2]

    const int tid  = threadIdx.x;
    const int lane = tid & 63;
    const int w    = tid >> 6;          // wave 0..7, cols [w*64, w*64+64)
    const int lr   = lane & 15;
    const int lg   = lane >> 4;
    const size_t row0 = (size_t)blockIdx.x * ROWS2;
    const unsigned short* abase = (const unsigned short*)out;  // bf16 A region

    // stage A (bf16, low half of each row's f32 slot) -> LDS, straight 16B copy.
    #pragma unroll
    for (int it = 0; it < 12; ++it) {
        int idx = it * THREADS2 + tid;
        int r = idx >> 6, c8 = (idx & 63) << 3;
        uint4 v = *(const uint4*)(abase + (row0 + r) * 1024 + c8);
        *(uint4*)(Ast + xswc(r, c8)) = v;
    }
    __syncthreads();

    f32x4 Y[6][4];
    #pragma unroll
    for (int mt = 0; mt < 6; ++mt)
        #pragma unroll
        for (int nt = 0; nt < 4; ++nt) Y[mt][nt] = (f32x4){0.f, 0.f, 0.f, 0.f};

    const unsigned short* obase = wt + (size_t)3 * WMAT + (w * 64 + lr) * D_DIM;
    #pragma unroll 1
    for (int ks = 0; ks < 16; ++ks) {
        bf16x8 afr[6];
        #pragma unroll
        for (int mt = 0; mt < 6; ++mt)
            afr[mt] = *(const bf16x8*)(Ast + xswc(mt * 16 + lr, ks * 32 + lg * 8));
        #pragma unroll
        for (int nt = 0; nt < 4; ++nt) {
            bf16x8 bfr = *(const bf16x8*)(obase + nt * 16 * D_DIM + ks * 32 + lg * 8);
            #pragma unroll
            for (int mt = 0; mt < 6; ++mt)
                Y[mt][nt] = __builtin_amdgcn_mfma_f32_16x16x32_bf16(afr[mt], bfr, Y[mt][nt], 0, 0, 0);
        }
    }

    // epilogue: +bo, +x (fp32), LayerNorm, store
    float bo4[4], gm4[4], bt4[4];
    int cols[4];
    #pragma unroll
    for (int nt = 0; nt < 4; ++nt) {
        cols[nt] = w * 64 + nt * 16 + lr;
        bo4[nt] = bo[cols[nt]]; gm4[nt] = gamma[cols[nt]]; bt4[nt] = beta[cols[nt]];
    }
    #pragma unroll
    for (int mt = 0; mt < 6; ++mt)
        #pragma unroll
        for (int j = 0; j < 4; ++j) {
            int rowl = mt * 16 + lg * 4 + j;
            const float* xrow = x + (row0 + rowl) * (size_t)D_DIM;
            float ps = 0.f, pq = 0.f;
            #pragma unroll
            for (int nt = 0; nt < 4; ++nt) {
                float y = Y[mt][nt][j] + bo4[nt] + xrow[cols[nt]];
                Y[mt][nt][j] = y;
                ps += y; pq += y * y;
            }
            ps += __shfl_xor(ps, 1); pq += __shfl_xor(pq, 1);
            ps += __shfl_xor(ps, 2); pq += __shfl_xor(pq, 2);
            ps += __shfl_xor(ps, 4); pq += __shfl_xor(pq, 4);
            ps += __shfl_xor(ps, 8); pq += __shfl_xor(pq, 8);
            if (lr == 0) { red[rowl * 17 + w * 2] = ps; red[rowl * 17 + w * 2 + 1] = pq; }
        }
    __syncthreads();
    if (tid < ROWS2) {
        float s = 0.f, q = 0.f;
        #pragma unroll
        for (int w8 = 0; w8 < 8; ++w8) { s += red[tid * 17 + w8 * 2]; q += red[tid * 17 + w8 * 2 + 1]; }
        float mu = s * (1.f / 512.f);
        float var = q * (1.f / 512.f) - mu * mu;
        musig[tid * 2] = mu;
        musig[tid * 2 + 1] = rsqrtf(var + 1e-5f);
    }
    __syncthreads();
    #pragma unroll
    for (int mt = 0; mt < 6; ++mt)
        #pragma unroll
        for (int j = 0; j < 4; ++j) {
            int rowl = mt * 16 + lg * 4 + j;
            float mu = musig[rowl * 2], rs = musig[rowl * 2 + 1];
            float* orow = out + (row0 + rowl) * (size_t)D_DIM;
            #pragma unroll
            for (int nt = 0; nt < 4; ++nt)
                orow[cols[nt]] = (Y[mt][nt][j] - mu) * rs * gm4[nt] + bt4[nt];
        }
}

extern "C" void kernel_launch(void* const* d_in, const int* in_sizes, int n_in,
                              void* d_out, int out_size, void* d_ws, size_t ws_size,
                              hipStream_t stream) {
    (void)in_sizes; (void)n_in; (void)out_size; (void)ws_size;
    const float* x     = (const float*)d_in[0];
    const float* Wq    = (const float*)d_in[1];
    const float* bq    = (const float*)d_in[2];
    const float* Wk    = (const float*)d_in[3];
    const float* bk    = (const float*)d_in[4];
    const float* Wv    = (const float*)d_in[5];
    const float* bv    = (const float*)d_in[6];
    const float* adj   = (const float*)d_in[7];
    const float* Wo    = (const float*)d_in[8];
    const float* bo    = (const float*)d_in[9];
    const float* gamma = (const float*)d_in[10];
    const float* beta  = (const float*)d_in[11];
    unsigned short* wt = (unsigned short*)d_ws;      // 4 * 512*512 bf16 = 2 MiB

    prep_weights<<<4096, 256, 0, stream>>>(Wq, Wk, Wv, Wo, wt);
    qkv_attn<<<16384 / G_B1, THREADS1, SMEM1, stream>>>(
        x, wt, bq, bk, bv, adj, (unsigned short*)d_out);
    oproj_ln<<<16384 / G_B2, THREADS2, SMEM2, stream>>>(
        x, wt, bo, gamma, beta, (float*)d_out);
}